// Round 1
// baseline (5439.669 us; speedup 1.0000x reference)
//
#include <hip/hip_runtime.h>
#include <math.h>

#define NROWS 32768
#define DD 32
#define NSPLIT 16
#define HID 320
#define POUT 1008
#define NBINS 16
#define BOUNDF 3.0f
#define MBWF 0.001f
#define MBHF 0.001f
#define MDF 0.001f
#define MLF 0.025f
#define LOG2PIF 1.8378770664093453f

// ws layout in floats
#define WS_LP 0
#define WS_TBL 16
#define TBL_STRIDE 112
// per (coupling c, dim j) table at WS_TBL + (c*16+j)*TBL_STRIDE:
//  [0..16]  cumh (17 knots, y-space)
//  [17..33] cumw (17 knots, x-space)
//  [34..50] dv   (17 derivatives)
//  [51..66] widths (16)
//  [67..82] heights (16)
//  [83..98] lam (16)
#define WS_LADJ 4096
#define WS_Z (4096 + NROWS)

__device__ inline float softplusf(float x) {
    return (x > 0.f) ? (x + log1pf(expf(-x))) : log1pf(expf(x));
}

// Core inverse rational-linear spline formula, given the selected bin's params.
__device__ inline void rls_core(float y, float iw, float icw, float ih, float ich,
                                float il, float idv, float idvp1,
                                float* xo, float* lo_) {
    bool inside = (y >= -BOUNDF) && (y <= BOUNDF);
    float yc = fminf(fmaxf(y, -BOUNDF), BOUNDF);
    float idel = ih / iw;
    float wb = sqrtf(idv / idvp1);
    float wc = (il * idv + (1.f - il) * wb * idvp1) / idel;
    float ya = ich;
    float yb = ih + ich;
    float ym = ((1.f - il) * ya + il * wb * yb) / ((1.f - il) + il * wb);
    bool left = (yc <= ym);
    float num = left ? (il * (ya - yc))
                     : ((wc - il * wb) * yc + il * wb * yb - wc * ym);
    float den = left ? ((wc - 1.f) * yc + ya - wc * ym)
                     : ((wc - wb) * yc + wb * yb - wc * ym);
    float x = num / den * iw + icw;
    float dnum = (left ? (wc * il * (ym - ya))
                       : (wb * wc * (1.f - il) * (yb - ym))) * iw;
    float ladj = logf(dnum) - 2.f * logf(fabsf(den));
    *xo = inside ? x : y;
    *lo_ = inside ? ladj : 0.f;
}

// 1 block, 64 threads: build per-dim spline tables for both couplings + lp_aff.
__global__ void prep_kernel(const float* __restrict__ t1w, const float* __restrict__ t1h,
                            const float* __restrict__ t1d, const float* __restrict__ t1l,
                            const float* __restrict__ t2w, const float* __restrict__ t2h,
                            const float* __restrict__ t2d, const float* __restrict__ t2l,
                            const float* __restrict__ stds, float* __restrict__ ws) {
    int td = threadIdx.x;
    if (td == 32) {
        float lp = 0.f;
        for (int k = 0; k < DD; ++k) lp -= logf(10.f * stds[k]);
        ws[WS_LP] = lp;
    }
    if (td < 32) {
        int c = td >> 4, j = td & 15;  // c==0 -> t1 tables, c==1 -> t2 tables
        const float* wr = (c == 0 ? t1w : t2w) + j * NBINS;
        const float* hr = (c == 0 ? t1h : t2h) + j * NBINS;
        const float* dr = (c == 0 ? t1d : t2d) + j * (NBINS - 1);
        const float* lr = (c == 0 ? t1l : t2l) + j * NBINS;
        float* tb = ws + WS_TBL + (c * 16 + j) * TBL_STRIDE;
        float mw = -1e30f, mh = -1e30f;
        for (int b = 0; b < NBINS; ++b) { mw = fmaxf(mw, wr[b]); mh = fmaxf(mh, hr[b]); }
        float sw = 0.f, sh = 0.f;
        for (int b = 0; b < NBINS; ++b) { sw += expf(wr[b] - mw); sh += expf(hr[b] - mh); }
        float fw = (1.f - NBINS * MBWF) / sw;
        float fh = (1.f - NBINS * MBHF) / sh;
        float kx[17], ky[17];
        kx[0] = -BOUNDF; ky[0] = -BOUNDF;
        float cw = 0.f, ch = 0.f;
        for (int b = 0; b < NBINS; ++b) {
            cw += MBWF + fw * expf(wr[b] - mw);
            ch += MBHF + fh * expf(hr[b] - mh);
            kx[b + 1] = 2.f * BOUNDF * cw - BOUNDF;
            ky[b + 1] = 2.f * BOUNDF * ch - BOUNDF;
        }
        kx[16] = BOUNDF; ky[16] = BOUNDF;
        for (int b = 0; b < 17; ++b) { tb[b] = ky[b]; tb[17 + b] = kx[b]; }
        tb[34] = 1.f - MDF;
        for (int b = 1; b <= 15; ++b) tb[34 + b] = MDF + softplusf(dr[b - 1]);
        tb[50] = 1.f - MDF;
        for (int b = 0; b < NBINS; ++b) {
            tb[51 + b] = kx[b + 1] - kx[b];
            tb[67 + b] = ky[b + 1] - ky[b];
            tb[83 + b] = MLF + (1.f - 2.f * MLF) / (1.f + expf(-lr[b]));
        }
    }
}

__global__ void affine_kernel(const float* __restrict__ data, const float* __restrict__ means,
                              const float* __restrict__ stds, float* __restrict__ z,
                              float* __restrict__ ladj) {
    int i = blockIdx.x * blockDim.x + threadIdx.x;
    if (i < NROWS * DD) {
        int col = i & 31;
        z[i] = (data[i] - means[col]) / (10.f * stds[col]);
    }
    if (i < NROWS) ladj[i] = 0.f;
}

// Fused coupling inverse: spline1 (precomputed tables) -> MLP -> spline2 (per-sample params).
// 32 samples per block, 512 threads. All intermediates in LDS; p never hits HBM.
__global__ __launch_bounds__(512, 2) void coupling_kernel(
        float* __restrict__ z, float* __restrict__ ladj, const float* __restrict__ tbl,
        const float* __restrict__ W1, const float* __restrict__ b1,
        const float* __restrict__ W2, const float* __restrict__ b2,
        const float* __restrict__ W3, const float* __restrict__ b3) {
    __shared__ float xt[32][16];
    __shared__ float yt2[32][16];
    __shared__ float h1s[32 * 320];
    __shared__ float h2s[32 * 320];
    __shared__ float pt[32 * 257];   // stride 257: conflict-free column reads
    __shared__ float lacc[32];
    const int t = threadIdx.x;
    const int n0 = blockIdx.x * 32;

    if (t < 32) lacc[t] = 0.f;
    __syncthreads();

    // ---- phase 1: spline1 on dims 0..15, stash y2, write x1 ----
    {
        int row = t >> 4, jd = t & 15;
        float y1 = z[(n0 + row) * DD + jd];
        float y2 = z[(n0 + row) * DD + NSPLIT + jd];
        yt2[row][jd] = y2;
        const float* tb = tbl + jd * TBL_STRIDE;
        float yc = fminf(fmaxf(y1, -BOUNDF), BOUNDF);
        int idx = 0;
#pragma unroll
        for (int b = 1; b <= 16; ++b) idx += (yc >= tb[b]) ? 1 : 0;
        if (idx > 15) idx = 15;
        float x, l;
        rls_core(y1, tb[51 + idx], tb[17 + idx], tb[67 + idx], tb[idx],
                 tb[83 + idx], tb[34 + idx], tb[35 + idx], &x, &l);
        xt[row][jd] = x;
        z[(n0 + row) * DD + jd] = x;
        atomicAdd(&lacc[row], l);
    }
    __syncthreads();

    // ---- phase 2: h1 = relu(x1 @ W1 + b1), K=16 ----
#pragma unroll
    for (int it = 0; it < 20; ++it) {
        int idx = it * 512 + t;
        int row = idx / 320;
        int col = idx - row * 320;
        float acc = b1[col];
#pragma unroll
        for (int k = 0; k < 16; ++k) acc += xt[row][k] * W1[k * HID + col];
        h1s[idx] = fmaxf(acc, 0.f);
    }
    __syncthreads();

    // ---- phase 3: h2 = relu(h1 @ W2 + b2), K=320, thread tile 4x5 ----
    {
        int rg = t >> 6, ct = t & 63;
        float acc[4][5];
#pragma unroll
        for (int j = 0; j < 5; ++j) {
            float bv = b2[ct + 64 * j];
#pragma unroll
            for (int i = 0; i < 4; ++i) acc[i][j] = bv;
        }
#pragma unroll 4
        for (int k = 0; k < 320; ++k) {
            float a[4], bb[5];
#pragma unroll
            for (int i = 0; i < 4; ++i) a[i] = h1s[(rg * 4 + i) * 320 + k];
#pragma unroll
            for (int j = 0; j < 5; ++j) bb[j] = W2[k * HID + ct + 64 * j];
#pragma unroll
            for (int i = 0; i < 4; ++i)
#pragma unroll
                for (int j = 0; j < 5; ++j) acc[i][j] += a[i] * bb[j];
        }
#pragma unroll
        for (int i = 0; i < 4; ++i)
#pragma unroll
            for (int j = 0; j < 5; ++j)
                h2s[(rg * 4 + i) * 320 + ct + 64 * j] = fmaxf(acc[i][j], 0.f);
    }
    __syncthreads();

    // ---- phase 4: p = h2 @ W3 + b3 in 4 chunks of 4 spline-dims, fused spline2 ----
    for (int jb = 0; jb < 4; ++jb) {
        {
            int rg = t >> 6, ct = t & 63;
            int cols[4];
            float bias[4];
#pragma unroll
            for (int q = 0; q < 4; ++q) {
                int m = ct * 4 + q;
                int sub = m & 63;
                int j = jb * 4 + (m >> 6);
                int col;
                if (sub < 16)      col = j * 16 + sub;              // w_raw
                else if (sub < 32) col = 256 + j * 16 + (sub - 16); // h_raw
                else if (sub < 47) col = 512 + j * 15 + (sub - 32); // d_raw (15)
                else if (sub == 47) col = -1;                       // pad
                else               col = 752 + j * 16 + (sub - 48); // l_raw
                cols[q] = (col < 0) ? 0 : col;
                bias[q] = (col < 0) ? 0.f : b3[cols[q]];
            }
            float acc[4][4];
#pragma unroll
            for (int i = 0; i < 4; ++i)
#pragma unroll
                for (int q = 0; q < 4; ++q) acc[i][q] = bias[q];
#pragma unroll 4
            for (int k = 0; k < 320; ++k) {
                float a[4], bb[4];
#pragma unroll
                for (int i = 0; i < 4; ++i) a[i] = h2s[(rg * 4 + i) * 320 + k];
#pragma unroll
                for (int q = 0; q < 4; ++q) bb[q] = W3[k * POUT + cols[q]];
#pragma unroll
                for (int i = 0; i < 4; ++i)
#pragma unroll
                    for (int q = 0; q < 4; ++q) acc[i][q] += a[i] * bb[q];
            }
#pragma unroll
            for (int i = 0; i < 4; ++i)
#pragma unroll
                for (int q = 0; q < 4; ++q)
                    pt[(rg * 4 + i) * 257 + ct * 4 + q] = acc[i][q];
        }
        __syncthreads();
        if (t < 128) {
            int row = t & 31, jl = t >> 5;
            int j = jb * 4 + jl;
            const float* pp = &pt[row * 257 + jl * 64];
            float y = yt2[row][j];
            // softmax normalizers for w (pp[0..15]) and h (pp[16..31])
            float mw = -1e30f, mh = -1e30f;
#pragma unroll
            for (int b = 0; b < 16; ++b) {
                mw = fmaxf(mw, pp[b]);
                mh = fmaxf(mh, pp[16 + b]);
            }
            float sw = 0.f, sh = 0.f;
#pragma unroll
            for (int b = 0; b < 16; ++b) {
                sw += expf(pp[b] - mw);
                sh += expf(pp[16 + b] - mh);
            }
            float fw = (1.f - NBINS * MBWF) / sw;
            float fh = (1.f - NBINS * MBHF) / sh;
            float yc = fminf(fmaxf(y, -BOUNDF), BOUNDF);
            // scan bins, select params of the bin containing yc (register-only)
            float cw = -BOUNDF, ch = -BOUNDF;
            float cumw = 0.f, cumh = 0.f;
            float dprev = 1.f - MDF;
            float iw = 1.f, icw = 0.f, ih = 1.f, ich = 0.f, il = 0.5f, idv = 1.f, idvp1 = 1.f;
#pragma unroll
            for (int b = 0; b < 16; ++b) {
                cumw += MBWF + fw * expf(pp[b] - mw);
                cumh += MBHF + fh * expf(pp[16 + b] - mh);
                float cwn = (b == 15) ? BOUNDF : (2.f * BOUNDF * cumw - BOUNDF);
                float chn = (b == 15) ? BOUNDF : (2.f * BOUNDF * cumh - BOUNDF);
                float dnext = (b == 15) ? (1.f - MDF) : (MDF + softplusf(pp[32 + b]));
                float lamb = MLF + (1.f - 2.f * MLF) / (1.f + expf(-pp[48 + b]));
                if (yc >= ch) {
                    iw = cwn - cw; icw = cw; ih = chn - ch; ich = ch;
                    il = lamb; idv = dprev; idvp1 = dnext;
                }
                cw = cwn; ch = chn; dprev = dnext;
            }
            float x, l;
            rls_core(y, iw, icw, ih, ich, il, idv, idvp1, &x, &l);
            z[(n0 + row) * DD + NSPLIT + j] = x;
            atomicAdd(&lacc[row], l);
        }
        __syncthreads();
    }
    if (t < 32) ladj[n0 + t] += lacc[t];
}

__global__ void final_kernel(const float* __restrict__ z, const float* __restrict__ ladj,
                             const float* __restrict__ ws, float* __restrict__ out) {
    int n = blockIdx.x * blockDim.x + threadIdx.x;
    if (n >= NROWS) return;
    float lp = ws[WS_LP];
    const float* zr = z + n * DD;
    float ss = 0.f;
#pragma unroll
    for (int k = 0; k < DD; ++k) ss += zr[k] * zr[k];
    out[n] = -0.5f * ss - 0.5f * DD * LOG2PIF + ladj[n] + lp;
}

extern "C" void kernel_launch(void* const* d_in, const int* in_sizes, int n_in,
                              void* d_out, int out_size, void* d_ws, size_t ws_size,
                              hipStream_t stream) {
    const float* data  = (const float*)d_in[0];
    const float* means = (const float*)d_in[1];
    const float* stds  = (const float*)d_in[2];
    const float* t1w = (const float*)d_in[3];
    const float* t1h = (const float*)d_in[4];
    const float* t1d = (const float*)d_in[5];
    const float* t1l = (const float*)d_in[6];
    const float* t1W1 = (const float*)d_in[7];
    const float* t1b1 = (const float*)d_in[8];
    const float* t1W2 = (const float*)d_in[9];
    const float* t1b2 = (const float*)d_in[10];
    const float* t1W3 = (const float*)d_in[11];
    const float* t1b3 = (const float*)d_in[12];
    const float* t2w = (const float*)d_in[13];
    const float* t2h = (const float*)d_in[14];
    const float* t2d = (const float*)d_in[15];
    const float* t2l = (const float*)d_in[16];
    const float* t2W1 = (const float*)d_in[17];
    const float* t2b1 = (const float*)d_in[18];
    const float* t2W2 = (const float*)d_in[19];
    const float* t2b2 = (const float*)d_in[20];
    const float* t2W3 = (const float*)d_in[21];
    const float* t2b3 = (const float*)d_in[22];

    float* ws = (float*)d_ws;
    float* ladj = ws + WS_LADJ;
    float* z = ws + WS_Z;

    prep_kernel<<<1, 64, 0, stream>>>(t1w, t1h, t1d, t1l, t2w, t2h, t2d, t2l, stds, ws);
    affine_kernel<<<(NROWS * DD) / 256, 256, 0, stream>>>(data, means, stds, z, ladj);
    // flow inverse: t2 coupling first (tables slot c=1), then t1 (slot c=0)
    coupling_kernel<<<NROWS / 32, 512, 0, stream>>>(
        z, ladj, ws + WS_TBL + 16 * TBL_STRIDE,
        t2W1, t2b1, t2W2, t2b2, t2W3, t2b3);
    coupling_kernel<<<NROWS / 32, 512, 0, stream>>>(
        z, ladj, ws + WS_TBL,
        t1W1, t1b1, t1W2, t1b2, t1W3, t1b3);
    final_kernel<<<(NROWS + 255) / 256, 256, 0, stream>>>(z, ladj, ws, (float*)d_out);
}

// Round 2
// 694.673 us; speedup vs baseline: 7.8305x; 7.8305x over previous
//
#include <hip/hip_runtime.h>
#include <math.h>

#define NROWS 32768
#define DD 32
#define HID 320
#define NBINS 16
#define BOUNDF 3.0f
#define MBWF 0.001f
#define MBHF 0.001f
#define MDF 0.001f
#define MLF 0.025f
#define LOG2PIF 1.8378770664093453f

// ---------------- ws layout ----------------
// floats:
#define WS_LP 0
#define WS_TBL 16
#define TBL_STRIDE 112
// per (c, dim j) table at WS_TBL + (c*16+j)*TBL_STRIDE:
//  [0..16] cumh | [17..33] cumw | [34..50] dv | [51..66] widths | [67..82] heights | [83..98] lam
#define WS_B3P 4096          // 2 x 1024 floats (slot 0 = t2, slot 1 = t1)
// bytes (bf16 weight region):
#define W2T_BYTE 32768       // 2 x 320*320 ushort (slot 0 = t2, slot 1 = t1)
#define W3T_BYTE 442368      // 2 x 1024*320 ushort
// total ws use: ~1.68 MB (known-good budget >= 4.2 MB from round 1)

typedef __attribute__((ext_vector_type(8))) unsigned short ushort8_t;
typedef __attribute__((ext_vector_type(8))) __bf16 bf16x8;
typedef __attribute__((ext_vector_type(4))) float f32x4;

__device__ __forceinline__ unsigned short f2bf(float x) {   // RNE, pure-int (finite inputs)
    unsigned u = __builtin_bit_cast(unsigned, x);
    return (unsigned short)((u + 0x7FFFu + ((u >> 16) & 1u)) >> 16);
}
__device__ __forceinline__ float bf2f(unsigned short s) {
    return __builtin_bit_cast(float, (unsigned)s << 16);
}
__device__ __forceinline__ f32x4 mfma_bf16(ushort8_t a, ushort8_t b, f32x4 c) {
    return __builtin_amdgcn_mfma_f32_16x16x32_bf16(
        __builtin_bit_cast(bf16x8, a), __builtin_bit_cast(bf16x8, b), c, 0, 0, 0);
}

__device__ __forceinline__ float softplusf(float x) {
    return (x > 0.f) ? (x + log1pf(expf(-x))) : log1pf(expf(x));
}

// Inverse monotonic rational-linear spline, selected-bin core.
__device__ __forceinline__ void rls_core(float y, float iw, float icw, float ih, float ich,
                                         float il, float idv, float idvp1,
                                         float* xo, float* lo_) {
    bool inside = (y >= -BOUNDF) && (y <= BOUNDF);
    float yc = fminf(fmaxf(y, -BOUNDF), BOUNDF);
    float idel = ih / iw;
    float wb = sqrtf(idv / idvp1);
    float wc = (il * idv + (1.f - il) * wb * idvp1) / idel;
    float ya = ich;
    float yb = ih + ich;
    float ym = ((1.f - il) * ya + il * wb * yb) / ((1.f - il) + il * wb);
    bool left = (yc <= ym);
    float num = left ? (il * (ya - yc)) : ((wc - il * wb) * yc + il * wb * yb - wc * ym);
    float den = left ? ((wc - 1.f) * yc + ya - wc * ym) : ((wc - wb) * yc + wb * yb - wc * ym);
    float x = num / den * iw + icw;
    float dnum = (left ? (wc * il * (ym - ya)) : (wb * wc * (1.f - il) * (yb - ym))) * iw;
    float ladj = logf(dnum) - 2.f * logf(fabsf(den));
    *xo = inside ? x : y;
    *lo_ = inside ? ladj : 0.f;
}

// permuted W3 column map: np in [0,1024) -> original p column (or -1 = zero pad)
__device__ __forceinline__ int colmap(int np) {
    int j = np >> 6, s = np & 63;
    if (s < 16) return j * 16 + s;
    if (s < 32) return 256 + j * 16 + (s - 16);
    if (s < 47) return 512 + j * 15 + (s - 32);
    if (s == 47) return -1;
    return 752 + j * 16 + (s - 48);
}

// ---- prep 1: spline1 tables + lp_aff (1 block, 64 threads). c=0 -> t1, c=1 -> t2.
__global__ void prep_tables(const float* __restrict__ t1w, const float* __restrict__ t1h,
                            const float* __restrict__ t1d, const float* __restrict__ t1l,
                            const float* __restrict__ t2w, const float* __restrict__ t2h,
                            const float* __restrict__ t2d, const float* __restrict__ t2l,
                            const float* __restrict__ stds, float* __restrict__ ws) {
    int td = threadIdx.x;
    if (td == 32) {
        float lp = 0.f;
        for (int k = 0; k < DD; ++k) lp -= logf(10.f * stds[k]);
        ws[WS_LP] = lp;
    }
    if (td < 32) {
        int c = td >> 4, j = td & 15;
        const float* wr = (c == 0 ? t1w : t2w) + j * NBINS;
        const float* hr = (c == 0 ? t1h : t2h) + j * NBINS;
        const float* dr = (c == 0 ? t1d : t2d) + j * (NBINS - 1);
        const float* lr = (c == 0 ? t1l : t2l) + j * NBINS;
        float* tb = ws + WS_TBL + (c * 16 + j) * TBL_STRIDE;
        float mw = -1e30f, mh = -1e30f;
        for (int b = 0; b < NBINS; ++b) { mw = fmaxf(mw, wr[b]); mh = fmaxf(mh, hr[b]); }
        float sw = 0.f, sh = 0.f;
        for (int b = 0; b < NBINS; ++b) { sw += expf(wr[b] - mw); sh += expf(hr[b] - mh); }
        float fw = (1.f - NBINS * MBWF) / sw;
        float fh = (1.f - NBINS * MBHF) / sh;
        float kx[17], ky[17];
        kx[0] = -BOUNDF; ky[0] = -BOUNDF;
        float cw = 0.f, ch = 0.f;
        for (int b = 0; b < NBINS; ++b) {
            cw += MBWF + fw * expf(wr[b] - mw);
            ch += MBHF + fh * expf(hr[b] - mh);
            kx[b + 1] = 2.f * BOUNDF * cw - BOUNDF;
            ky[b + 1] = 2.f * BOUNDF * ch - BOUNDF;
        }
        kx[16] = BOUNDF; ky[16] = BOUNDF;
        for (int b = 0; b < 17; ++b) { tb[b] = ky[b]; tb[17 + b] = kx[b]; }
        tb[34] = 1.f - MDF;
        for (int b = 1; b <= 15; ++b) tb[34 + b] = MDF + softplusf(dr[b - 1]);
        tb[50] = 1.f - MDF;
        for (int b = 0; b < NBINS; ++b) {
            tb[51 + b] = kx[b + 1] - kx[b];
            tb[67 + b] = ky[b + 1] - ky[b];
            tb[83 + b] = MLF + (1.f - 2.f * MLF) / (1.f + expf(-lr[b]));
        }
    }
}

// ---- prep 2: bf16 transposed weights into ws. slot 0 = t2, slot 1 = t1.
__global__ void prep_weights(const float* __restrict__ t2W2, const float* __restrict__ t1W2,
                             const float* __restrict__ t2W3, const float* __restrict__ t1W3,
                             const float* __restrict__ t2b3, const float* __restrict__ t1b3,
                             unsigned short* __restrict__ w2t, unsigned short* __restrict__ w3t,
                             float* __restrict__ b3p) {
    int id = blockIdx.x * 512 + threadIdx.x;
    if (id < 204800) {                       // W2t[c][n*320+k] = W2_c[k][n]
        int c = id / 102400;
        int rem = id - c * 102400;
        int k = rem / 320, n = rem - k * 320;
        const float* W2 = c ? t1W2 : t2W2;
        w2t[c * 102400 + n * 320 + k] = f2bf(W2[k * 320 + n]);
    } else if (id < 860160) {                // W3t[c][np*320+k] = W3_c[k][colmap(np)]
        int id2 = id - 204800;
        int c = id2 / 327680;
        int rem = id2 - c * 327680;
        int k = rem / 1024, np = rem - k * 1024;
        int col = colmap(np);
        const float* W3 = c ? t1W3 : t2W3;
        w3t[(size_t)c * 327680 + (size_t)np * 320 + k] =
            f2bf(col < 0 ? 0.f : W3[(size_t)k * 1008 + col]);
    } else if (id < 862208) {                // b3p
        int idb = id - 860160;
        int c = idb / 1024, np = idb - c * 1024;
        int col = colmap(np);
        const float* b3 = c ? t1b3 : t2b3;
        b3p[c * 1024 + np] = (col < 0) ? 0.f : b3[col];
    }
}

// ---------------- fused coupling (device fn, called twice) ----------------
// zs[32][33] holds the 32-sample z state; h1b/h2b are swizzled bf16 [32][320];
// pts is swizzled bf16 [32][520] holding one 512-col chunk of p.
__device__ __forceinline__ void coupling(
        int t, float (*zs)[33], float* lacc,
        unsigned short* h1b, unsigned short* h2b, unsigned short* pts,
        const float* __restrict__ tbl,
        const float* __restrict__ W1, const float* __restrict__ b1,
        const unsigned short* __restrict__ w2t, const float* __restrict__ b2,
        const unsigned short* __restrict__ w3t, const float* __restrict__ b3p) {
    const int l = t & 63, w = t >> 6;
    const int wm = w >> 2, wn = w & 3;

    // ---- phase 1: spline1 on dims 0..15 (1 task/thread) ----
    {
        int row = t >> 4, jd = t & 15;
        float y1 = zs[row][jd];
        const float* tb = tbl + jd * TBL_STRIDE;
        float yc = fminf(fmaxf(y1, -BOUNDF), BOUNDF);
        int idx = 0;
#pragma unroll
        for (int b = 1; b <= 16; ++b) idx += (yc >= tb[b]) ? 1 : 0;
        if (idx > 15) idx = 15;
        float x, lv;
        rls_core(y1, tb[51 + idx], tb[17 + idx], tb[67 + idx], tb[idx],
                 tb[83 + idx], tb[34 + idx], tb[35 + idx], &x, &lv);
        zs[row][jd] = x;
        atomicAdd(&lacc[row], lv);
    }
    __syncthreads();

    // ---- phase 2: h1 = relu(x1 @ W1 + b1), fp32 VALU (K=16) -> swizzled bf16 LDS ----
    {
        int cb = t & 63, rg = t >> 6;     // cols cb+64j, rows rg*4+i
        float acc[4][5];
#pragma unroll
        for (int j = 0; j < 5; ++j) {
            float bv = b1[cb + 64 * j];
#pragma unroll
            for (int i = 0; i < 4; ++i) acc[i][j] = bv;
        }
#pragma unroll
        for (int k = 0; k < 16; ++k) {
            float xv[4];
#pragma unroll
            for (int i = 0; i < 4; ++i) xv[i] = zs[rg * 4 + i][k];
#pragma unroll
            for (int j = 0; j < 5; ++j) {
                float wv = W1[k * HID + cb + 64 * j];
#pragma unroll
                for (int i = 0; i < 4; ++i) acc[i][j] += xv[i] * wv;
            }
        }
#pragma unroll
        for (int i = 0; i < 4; ++i) {
            int row = rg * 4 + i;
#pragma unroll
            for (int j = 0; j < 5; ++j) {
                int col = cb + 64 * j;
                h1b[row * 320 + (col ^ ((row & 7) << 3))] = f2bf(fmaxf(acc[i][j], 0.f));
            }
        }
    }
    __syncthreads();

    // ---- phase 3: h2 = relu(h1 @ W2 + b2) via MFMA (M=32,N=320,K=320) ----
    {
        const int mrow = wm * 16 + (l & 15);
        const int koff = (l >> 4) << 3;
        f32x4 acc[5];
        f32x4 z4 = {0.f, 0.f, 0.f, 0.f};
#pragma unroll
        for (int nt = 0; nt < 5; ++nt) acc[nt] = z4;
#pragma unroll
        for (int kt = 0; kt < 10; ++kt) {
            int k = kt * 32 + koff;
            ushort8_t a8 = *(const ushort8_t*)&h1b[mrow * 320 + (k ^ ((mrow & 7) << 3))];
#pragma unroll
            for (int nt = 0; nt < 5; ++nt) {
                int n = wn * 80 + nt * 16 + (l & 15);
                ushort8_t b8 = *(const ushort8_t*)&w2t[n * 320 + k];
                acc[nt] = mfma_bf16(a8, b8, acc[nt]);
            }
        }
#pragma unroll
        for (int nt = 0; nt < 5; ++nt) {
            int n = wn * 80 + nt * 16 + (l & 15);
            float bias = b2[n];
#pragma unroll
            for (int r = 0; r < 4; ++r) {
                int row = wm * 16 + ((l >> 4) << 2) + r;
                float v = fmaxf(acc[nt][r] + bias, 0.f);
                h2b[row * 320 + (n ^ ((row & 7) << 3))] = f2bf(v);
            }
        }
    }
    __syncthreads();

    // ---- phase 4+5: p-chunk GEMM (N=512) then in-register spline2 (8 dims/chunk) ----
    for (int ch = 0; ch < 2; ++ch) {
        {
            const int mrow = wm * 16 + (l & 15);
            const int koff = (l >> 4) << 3;
            f32x4 acc[8];
            f32x4 z4 = {0.f, 0.f, 0.f, 0.f};
#pragma unroll
            for (int nt = 0; nt < 8; ++nt) acc[nt] = z4;
#pragma unroll
            for (int kt = 0; kt < 10; ++kt) {
                int k = kt * 32 + koff;
                ushort8_t a8 = *(const ushort8_t*)&h2b[mrow * 320 + (k ^ ((mrow & 7) << 3))];
#pragma unroll
                for (int nt = 0; nt < 8; ++nt) {
                    int ng = ch * 512 + wn * 128 + nt * 16 + (l & 15);
                    ushort8_t b8 = *(const ushort8_t*)&w3t[(size_t)ng * 320 + k];
                    acc[nt] = mfma_bf16(a8, b8, acc[nt]);
                }
            }
#pragma unroll
            for (int nt = 0; nt < 8; ++nt) {
                int ng = ch * 512 + wn * 128 + nt * 16 + (l & 15);
                float bias = b3p[ng];
                int nl = wn * 128 + nt * 16 + (l & 15);   // chunk-local col
                int js = nl >> 6;
#pragma unroll
                for (int r = 0; r < 4; ++r) {
                    int row = wm * 16 + ((l >> 4) << 2) + r;
                    pts[row * 520 + (nl ^ (js << 3))] = f2bf(acc[nt][r] + bias);
                }
            }
        }
        __syncthreads();
        if (t < 256) {
            int row = t >> 3, jl = t & 7;
            int j = ch * 8 + jl;
            float y = zs[row][16 + j];
            const unsigned short* pr = &pts[row * 520];
            // unpack w,h raw (chunks 0..3)
            float pw[16], ph[16];
#pragma unroll
            for (int c = 0; c < 4; ++c) {
                ushort8_t u = *(const ushort8_t*)&pr[(jl * 64 + c * 8) ^ (jl << 3)];
#pragma unroll
                for (int q = 0; q < 8; ++q) {
                    int i = c * 8 + q;
                    float f = bf2f(u[q]);
                    if (i < 16) pw[i] = f; else ph[i - 16] = f;
                }
            }
            float mw = -1e30f, mh = -1e30f;
#pragma unroll
            for (int b = 0; b < 16; ++b) { mw = fmaxf(mw, pw[b]); mh = fmaxf(mh, ph[b]); }
            float ew[16], eh[16];
            float sw = 0.f, sh = 0.f;
#pragma unroll
            for (int b = 0; b < 16; ++b) {
                ew[b] = expf(pw[b] - mw); eh[b] = expf(ph[b] - mh);
                sw += ew[b]; sh += eh[b];
            }
            // unpack d,l raw (chunks 4..7)
            float dl[32];
#pragma unroll
            for (int c = 4; c < 8; ++c) {
                ushort8_t u = *(const ushort8_t*)&pr[(jl * 64 + c * 8) ^ (jl << 3)];
#pragma unroll
                for (int q = 0; q < 8; ++q) dl[(c - 4) * 8 + q] = bf2f(u[q]);
            }
            float fw = (1.f - NBINS * MBWF) / sw;
            float fh = (1.f - NBINS * MBHF) / sh;
            float yc = fminf(fmaxf(y, -BOUNDF), BOUNDF);
            float cw = -BOUNDF, chh = -BOUNDF, cumw = 0.f, cumh = 0.f;
            float dprev = 1.f - MDF;
            float iw = 1.f, icw = 0.f, ih = 1.f, ich = 0.f, il = 0.5f, idv = 1.f, idvp1 = 1.f;
#pragma unroll
            for (int b = 0; b < 16; ++b) {
                cumw += MBWF + fw * ew[b];
                cumh += MBHF + fh * eh[b];
                float cwn = (b == 15) ? BOUNDF : (2.f * BOUNDF * cumw - BOUNDF);
                float chn = (b == 15) ? BOUNDF : (2.f * BOUNDF * cumh - BOUNDF);
                float dnext = (b == 15) ? (1.f - MDF) : (MDF + softplusf(dl[b]));
                float lamb = MLF + (1.f - 2.f * MLF) / (1.f + expf(-dl[16 + b]));
                if (yc >= chh) {
                    iw = cwn - cw; icw = cw; ih = chn - chh; ich = chh;
                    il = lamb; idv = dprev; idvp1 = dnext;
                }
                cw = cwn; chh = chn; dprev = dnext;
            }
            float x, lv;
            rls_core(y, iw, icw, ih, ich, il, idv, idvp1, &x, &lv);
            zs[row][16 + j] = x;
            atomicAdd(&lacc[row], lv);
        }
        __syncthreads();
    }
}

// ---------------- fused main kernel: affine + coupling(t2) + coupling(t1) + final ----------------
__global__ __launch_bounds__(512, 4) void fused_kernel(
        const float* __restrict__ data, const float* __restrict__ means,
        const float* __restrict__ stds, const float* __restrict__ ws,
        const unsigned short* __restrict__ w2t, const unsigned short* __restrict__ w3t,
        const float* __restrict__ t2W1, const float* __restrict__ t2b1, const float* __restrict__ t2b2,
        const float* __restrict__ t1W1, const float* __restrict__ t1b1, const float* __restrict__ t1b2,
        float* __restrict__ out) {
    __shared__ float zs[32][33];
    __shared__ float lacc[32];
    __shared__ unsigned short h1b[32 * 320];
    __shared__ unsigned short h2b[32 * 320];
    __shared__ unsigned short pts[32 * 520];
    // LDS total: 4224+128+20480+20480+33280 = 78592 B -> 2 blocks/CU

    const int t = threadIdx.x;
    const int n0 = blockIdx.x * 32;

    // phase 0: affine z2 = (data - mu) / (10 sigma), float2 per thread
    {
        const float2* dp = (const float2*)(data + (size_t)n0 * DD);
        float2 v = dp[t];
        int row = t >> 4, c = (t & 15) * 2;
        zs[row][c]     = (v.x - means[c])     / (10.f * stds[c]);
        zs[row][c + 1] = (v.y - means[c + 1]) / (10.f * stds[c + 1]);
        if (t < 32) lacc[t] = 0.f;
    }
    __syncthreads();

    const float* tbl_t1 = ws + WS_TBL;
    const float* tbl_t2 = ws + WS_TBL + 16 * TBL_STRIDE;
    const float* b3p    = ws + WS_B3P;

    // t2 coupling (weight slot 0), then t1 (slot 1)
    coupling(t, zs, lacc, h1b, h2b, pts, tbl_t2, t2W1, t2b1,
             w2t, t2b2, w3t, b3p);
    coupling(t, zs, lacc, h1b, h2b, pts, tbl_t1, t1W1, t1b1,
             w2t + 102400, t1b2, w3t + 327680, b3p + 1024);

    // final: out = -0.5*||z0||^2 - 16*log(2pi) + ladj + lp_aff
    if (t < 32) {
        float lp = ws[WS_LP];
        float ss = 0.f;
#pragma unroll
        for (int c = 0; c < DD; ++c) ss += zs[t][c] * zs[t][c];
        out[n0 + t] = -0.5f * ss - 16.f * LOG2PIF + lacc[t] + lp;
    }
}

extern "C" void kernel_launch(void* const* d_in, const int* in_sizes, int n_in,
                              void* d_out, int out_size, void* d_ws, size_t ws_size,
                              hipStream_t stream) {
    const float* data  = (const float*)d_in[0];
    const float* means = (const float*)d_in[1];
    const float* stds  = (const float*)d_in[2];
    const float* t1w = (const float*)d_in[3];
    const float* t1h = (const float*)d_in[4];
    const float* t1d = (const float*)d_in[5];
    const float* t1l = (const float*)d_in[6];
    const float* t1W1 = (const float*)d_in[7];
    const float* t1b1 = (const float*)d_in[8];
    const float* t1W2 = (const float*)d_in[9];
    const float* t1b2 = (const float*)d_in[10];
    const float* t1W3 = (const float*)d_in[11];
    const float* t1b3 = (const float*)d_in[12];
    const float* t2w = (const float*)d_in[13];
    const float* t2h = (const float*)d_in[14];
    const float* t2d = (const float*)d_in[15];
    const float* t2l = (const float*)d_in[16];
    const float* t2W1 = (const float*)d_in[17];
    const float* t2b1 = (const float*)d_in[18];
    const float* t2W2 = (const float*)d_in[19];
    const float* t2b2 = (const float*)d_in[20];
    const float* t2W3 = (const float*)d_in[21];
    const float* t2b3 = (const float*)d_in[22];

    float* ws = (float*)d_ws;
    unsigned short* w2t = (unsigned short*)((char*)d_ws + W2T_BYTE);
    unsigned short* w3t = (unsigned short*)((char*)d_ws + W3T_BYTE);
    float* b3p = ws + WS_B3P;

    prep_tables<<<1, 64, 0, stream>>>(t1w, t1h, t1d, t1l, t2w, t2h, t2d, t2l, stds, ws);
    prep_weights<<<1684, 512, 0, stream>>>(t2W2, t1W2, t2W3, t1W3, t2b3, t1b3, w2t, w3t, b3p);
    fused_kernel<<<NROWS / 32, 512, 0, stream>>>(
        data, means, stds, ws, w2t, w3t,
        t2W1, t2b1, t2b2, t1W1, t1b1, t1b2, (float*)d_out);
}

// Round 3
// 629.756 us; speedup vs baseline: 8.6377x; 1.1031x over previous
//
#include <hip/hip_runtime.h>
#include <math.h>

#define NROWS 32768
#define DD 32
#define HID 320
#define NBINS 16
#define BOUNDF 3.0f
#define MBWF 0.001f
#define MBHF 0.001f
#define MDF 0.001f
#define MLF 0.025f
#define LOG2PIF 1.8378770664093453f

// ---------------- ws layout ----------------
#define WS_LP 0
#define WS_TBL 16
#define TBL_STRIDE 112
// per (c, dim j) table at WS_TBL + (c*16+j)*TBL_STRIDE:
//  [0..16] cumh | [17..33] cumw | [34..50] dv | [51..66] widths | [67..82] heights | [83..98] lam
#define WS_B3P 4096          // 2 x 1024 floats (slot 0 = t2, slot 1 = t1)
#define W2T_BYTE 32768       // 2 x 320*320 ushort
#define W3T_BYTE 442368      // 2 x 1024*320 ushort

typedef __attribute__((ext_vector_type(8))) unsigned short ushort8_t;
typedef __attribute__((ext_vector_type(8))) __bf16 bf16x8;
typedef __attribute__((ext_vector_type(4))) float f32x4;

__device__ __forceinline__ unsigned short f2bf(float x) {   // RNE, pure-int (finite inputs)
    unsigned u = __builtin_bit_cast(unsigned, x);
    return (unsigned short)((u + 0x7FFFu + ((u >> 16) & 1u)) >> 16);
}
__device__ __forceinline__ float bf2f(unsigned short s) {
    return __builtin_bit_cast(float, (unsigned)s << 16);
}
__device__ __forceinline__ f32x4 mfma_bf16(ushort8_t a, ushort8_t b, f32x4 c) {
    return __builtin_amdgcn_mfma_f32_16x16x32_bf16(
        __builtin_bit_cast(bf16x8, a), __builtin_bit_cast(bf16x8, b), c, 0, 0, 0);
}

__device__ __forceinline__ float softplus_precise(float x) {
    return (x > 0.f) ? (x + log1pf(expf(-x))) : log1pf(expf(x));
}
__device__ __forceinline__ float softplus_fast(float x) {
    return fmaxf(x, 0.f) + __logf(1.f + __expf(-fabsf(x)));
}

// Inverse monotonic rational-linear spline, selected-bin core (fast-log variant).
__device__ __forceinline__ void rls_core(float y, float iw, float icw, float ih, float ich,
                                         float il, float idv, float idvp1,
                                         float* xo, float* lo_) {
    bool inside = (y >= -BOUNDF) && (y <= BOUNDF);
    float yc = fminf(fmaxf(y, -BOUNDF), BOUNDF);
    float idel = ih / iw;
    float wb = sqrtf(idv / idvp1);
    float wc = (il * idv + (1.f - il) * wb * idvp1) / idel;
    float ya = ich;
    float yb = ih + ich;
    float ym = ((1.f - il) * ya + il * wb * yb) / ((1.f - il) + il * wb);
    bool left = (yc <= ym);
    float num = left ? (il * (ya - yc)) : ((wc - il * wb) * yc + il * wb * yb - wc * ym);
    float den = left ? ((wc - 1.f) * yc + ya - wc * ym) : ((wc - wb) * yc + wb * yb - wc * ym);
    float x = num / den * iw + icw;
    float dnum = (left ? (wc * il * (ym - ya)) : (wb * wc * (1.f - il) * (yb - ym))) * iw;
    float ladj = __logf(dnum) - 2.f * __logf(fabsf(den));
    *xo = inside ? x : y;
    *lo_ = inside ? ladj : 0.f;
}

// permuted W3 column map: np in [0,1024) -> original p column (or -1 = zero pad)
__device__ __forceinline__ int colmap(int np) {
    int j = np >> 6, s = np & 63;
    if (s < 16) return j * 16 + s;
    if (s < 32) return 256 + j * 16 + (s - 16);
    if (s < 47) return 512 + j * 15 + (s - 32);
    if (s == 47) return -1;
    return 752 + j * 16 + (s - 48);
}

// ---- prep 1: spline1 tables + lp_aff (1 block, 64 threads). c=0 -> t1, c=1 -> t2.
__global__ void prep_tables(const float* __restrict__ t1w, const float* __restrict__ t1h,
                            const float* __restrict__ t1d, const float* __restrict__ t1l,
                            const float* __restrict__ t2w, const float* __restrict__ t2h,
                            const float* __restrict__ t2d, const float* __restrict__ t2l,
                            const float* __restrict__ stds, float* __restrict__ ws) {
    int td = threadIdx.x;
    if (td == 32) {
        float lp = 0.f;
        for (int k = 0; k < DD; ++k) lp -= logf(10.f * stds[k]);
        ws[WS_LP] = lp;
    }
    if (td < 32) {
        int c = td >> 4, j = td & 15;
        const float* wr = (c == 0 ? t1w : t2w) + j * NBINS;
        const float* hr = (c == 0 ? t1h : t2h) + j * NBINS;
        const float* dr = (c == 0 ? t1d : t2d) + j * (NBINS - 1);
        const float* lr = (c == 0 ? t1l : t2l) + j * NBINS;
        float* tb = ws + WS_TBL + (c * 16 + j) * TBL_STRIDE;
        float mw = -1e30f, mh = -1e30f;
        for (int b = 0; b < NBINS; ++b) { mw = fmaxf(mw, wr[b]); mh = fmaxf(mh, hr[b]); }
        float sw = 0.f, sh = 0.f;
        for (int b = 0; b < NBINS; ++b) { sw += expf(wr[b] - mw); sh += expf(hr[b] - mh); }
        float fw = (1.f - NBINS * MBWF) / sw;
        float fh = (1.f - NBINS * MBHF) / sh;
        float kx[17], ky[17];
        kx[0] = -BOUNDF; ky[0] = -BOUNDF;
        float cw = 0.f, ch = 0.f;
        for (int b = 0; b < NBINS; ++b) {
            cw += MBWF + fw * expf(wr[b] - mw);
            ch += MBHF + fh * expf(hr[b] - mh);
            kx[b + 1] = 2.f * BOUNDF * cw - BOUNDF;
            ky[b + 1] = 2.f * BOUNDF * ch - BOUNDF;
        }
        kx[16] = BOUNDF; ky[16] = BOUNDF;
        for (int b = 0; b < 17; ++b) { tb[b] = ky[b]; tb[17 + b] = kx[b]; }
        tb[34] = 1.f - MDF;
        for (int b = 1; b <= 15; ++b) tb[34 + b] = MDF + softplus_precise(dr[b - 1]);
        tb[50] = 1.f - MDF;
        for (int b = 0; b < NBINS; ++b) {
            tb[51 + b] = kx[b + 1] - kx[b];
            tb[67 + b] = ky[b + 1] - ky[b];
            tb[83 + b] = MLF + (1.f - 2.f * MLF) / (1.f + expf(-lr[b]));
        }
    }
}

// ---- prep 2: bf16 transposed weights into ws. slot 0 = t2, slot 1 = t1.
__global__ void prep_weights(const float* __restrict__ t2W2, const float* __restrict__ t1W2,
                             const float* __restrict__ t2W3, const float* __restrict__ t1W3,
                             const float* __restrict__ t2b3, const float* __restrict__ t1b3,
                             unsigned short* __restrict__ w2t, unsigned short* __restrict__ w3t,
                             float* __restrict__ b3p) {
    int id = blockIdx.x * 512 + threadIdx.x;
    if (id < 204800) {                       // W2t[c][n*320+k] = W2_c[k][n]
        int c = id / 102400;
        int rem = id - c * 102400;
        int k = rem / 320, n = rem - k * 320;
        const float* W2 = c ? t1W2 : t2W2;
        w2t[c * 102400 + n * 320 + k] = f2bf(W2[k * 320 + n]);
    } else if (id < 860160) {                // W3t[c][np*320+k] = W3_c[k][colmap(np)]
        int id2 = id - 204800;
        int c = id2 / 327680;
        int rem = id2 - c * 327680;
        int k = rem / 1024, np = rem - k * 1024;
        int col = colmap(np);
        const float* W3 = c ? t1W3 : t2W3;
        w3t[(size_t)c * 327680 + (size_t)np * 320 + k] =
            f2bf(col < 0 ? 0.f : W3[(size_t)k * 1008 + col]);
    } else if (id < 862208) {                // b3p
        int idb = id - 860160;
        int c = idb / 1024, np = idb - c * 1024;
        int col = colmap(np);
        const float* b3 = c ? t1b3 : t2b3;
        b3p[c * 1024 + np] = (col < 0) ? 0.f : b3[col];
    }
}

// ---------------- fused coupling (device fn, called twice) ----------------
__device__ __forceinline__ void coupling(
        int t, float (*zs)[33], float* lacc,
        unsigned short* h1b, unsigned short* h2b, unsigned short* pts,
        const float* __restrict__ tbl,
        const float* __restrict__ W1, const float* __restrict__ b1,
        const unsigned short* __restrict__ w2t, const float* __restrict__ b2,
        const unsigned short* __restrict__ w3t, const float* __restrict__ b3p) {
    const int l = t & 63, w = t >> 6;
    const int wm = w >> 2, wn = w & 3;

    // ---- phase 1: spline1 on dims 0..15 (1 task/thread) ----
    {
        int row = t >> 4, jd = t & 15;
        float y1 = zs[row][jd];
        const float* tb = tbl + jd * TBL_STRIDE;
        float yc = fminf(fmaxf(y1, -BOUNDF), BOUNDF);
        int idx = 0;
#pragma unroll
        for (int b = 1; b <= 16; ++b) idx += (yc >= tb[b]) ? 1 : 0;
        if (idx > 15) idx = 15;
        float x, lv;
        rls_core(y1, tb[51 + idx], tb[17 + idx], tb[67 + idx], tb[idx],
                 tb[83 + idx], tb[34 + idx], tb[35 + idx], &x, &lv);
        zs[row][jd] = x;
        atomicAdd(&lacc[row], lv);
    }
    __syncthreads();

    // ---- phase 2: h1 = relu(x1 @ W1 + b1), fp32 VALU (K=16) -> swizzled bf16 LDS ----
    {
        int cb = t & 63, rg = t >> 6;
        float acc[4][5];
#pragma unroll
        for (int j = 0; j < 5; ++j) {
            float bv = b1[cb + 64 * j];
#pragma unroll
            for (int i = 0; i < 4; ++i) acc[i][j] = bv;
        }
#pragma unroll
        for (int k = 0; k < 16; ++k) {
            float xv[4];
#pragma unroll
            for (int i = 0; i < 4; ++i) xv[i] = zs[rg * 4 + i][k];
#pragma unroll
            for (int j = 0; j < 5; ++j) {
                float wv = W1[k * HID + cb + 64 * j];
#pragma unroll
                for (int i = 0; i < 4; ++i) acc[i][j] += xv[i] * wv;
            }
        }
#pragma unroll
        for (int i = 0; i < 4; ++i) {
            int row = rg * 4 + i;
#pragma unroll
            for (int j = 0; j < 5; ++j) {
                int col = cb + 64 * j;
                h1b[row * 320 + (col ^ ((row & 7) << 3))] = f2bf(fmaxf(acc[i][j], 0.f));
            }
        }
    }
    __syncthreads();

    // ---- phase 3: h2 = relu(h1 @ W2 + b2) via MFMA (M=32,N=320,K=320) ----
    {
        const int mrow = wm * 16 + (l & 15);
        const int koff = (l >> 4) << 3;
        f32x4 acc[5];
        f32x4 z4 = {0.f, 0.f, 0.f, 0.f};
#pragma unroll
        for (int nt = 0; nt < 5; ++nt) acc[nt] = z4;
#pragma unroll
        for (int kt = 0; kt < 10; ++kt) {
            int k = kt * 32 + koff;
            ushort8_t a8 = *(const ushort8_t*)&h1b[mrow * 320 + (k ^ ((mrow & 7) << 3))];
#pragma unroll
            for (int nt = 0; nt < 5; ++nt) {
                int n = wn * 80 + nt * 16 + (l & 15);
                ushort8_t b8 = *(const ushort8_t*)&w2t[n * 320 + k];
                acc[nt] = mfma_bf16(a8, b8, acc[nt]);
            }
        }
#pragma unroll
        for (int nt = 0; nt < 5; ++nt) {
            int n = wn * 80 + nt * 16 + (l & 15);
            float bias = b2[n];
#pragma unroll
            for (int r = 0; r < 4; ++r) {
                int row = wm * 16 + ((l >> 4) << 2) + r;
                float v = fmaxf(acc[nt][r] + bias, 0.f);
                h2b[row * 320 + (n ^ ((row & 7) << 3))] = f2bf(v);
            }
        }
    }
    __syncthreads();

    // ---- phase 4+5: p-chunk GEMM (N=512) then in-register spline2 (8 dims/chunk) ----
    for (int ch = 0; ch < 2; ++ch) {
        {
            const int mrow = wm * 16 + (l & 15);
            const int koff = (l >> 4) << 3;
            f32x4 acc[8];
            f32x4 z4 = {0.f, 0.f, 0.f, 0.f};
#pragma unroll
            for (int nt = 0; nt < 8; ++nt) acc[nt] = z4;
#pragma unroll
            for (int kt = 0; kt < 10; ++kt) {
                int k = kt * 32 + koff;
                ushort8_t a8 = *(const ushort8_t*)&h2b[mrow * 320 + (k ^ ((mrow & 7) << 3))];
#pragma unroll
                for (int nt = 0; nt < 8; ++nt) {
                    int ng = ch * 512 + wn * 128 + nt * 16 + (l & 15);
                    ushort8_t b8 = *(const ushort8_t*)&w3t[(size_t)ng * 320 + k];
                    acc[nt] = mfma_bf16(a8, b8, acc[nt]);
                }
            }
#pragma unroll
            for (int nt = 0; nt < 8; ++nt) {
                int ng = ch * 512 + wn * 128 + nt * 16 + (l & 15);
                float bias = b3p[ng];
                int nl = wn * 128 + nt * 16 + (l & 15);   // chunk-local col
                int js = nl >> 6;
#pragma unroll
                for (int r = 0; r < 4; ++r) {
                    int row = wm * 16 + ((l >> 4) << 2) + r;
                    pts[row * 520 + (nl ^ (js << 3))] = f2bf(acc[nt][r] + bias);
                }
            }
        }
        __syncthreads();
        // ---- spline2: no big register arrays, no scratch, fast transcendentals ----
        if (t < 256) {
            int row = t >> 3, jl = t & 7;
            int j = ch * 8 + jl;
            float y = zs[row][16 + j];
            const unsigned short* pr = &pts[row * 520];
            const int base = jl * 64, xr = jl << 3;
            // w_raw (s 0..15), h_raw (s 16..31) into 4x ushort8 (16 VGPRs, static extract)
            ushort8_t uw0 = *(const ushort8_t*)&pr[(base + 0) ^ xr];
            ushort8_t uw1 = *(const ushort8_t*)&pr[(base + 8) ^ xr];
            ushort8_t uh0 = *(const ushort8_t*)&pr[(base + 16) ^ xr];
            ushort8_t uh1 = *(const ushort8_t*)&pr[(base + 24) ^ xr];
            float mw = -1e30f, mh = -1e30f;
#pragma unroll
            for (int b = 0; b < 8; ++b) {
                mw = fmaxf(mw, fmaxf(bf2f(uw0[b]), bf2f(uw1[b])));
                mh = fmaxf(mh, fmaxf(bf2f(uh0[b]), bf2f(uh1[b])));
            }
            float sw = 0.f, sh = 0.f;
#pragma unroll
            for (int b = 0; b < 8; ++b) {
                sw += __expf(bf2f(uw0[b]) - mw) + __expf(bf2f(uw1[b]) - mw);
                sh += __expf(bf2f(uh0[b]) - mh) + __expf(bf2f(uh1[b]) - mh);
            }
            float fw = (1.f - NBINS * MBWF) / sw;
            float fh = (1.f - NBINS * MBHF) / sh;
            float yc = fminf(fmaxf(y, -BOUNDF), BOUNDF);
            float cw = -BOUNDF, chh = -BOUNDF, cumw = 0.f, cumh = 0.f;
            float iw = 1.f, icw = 0.f, ih = 1.f, ich = 0.f;
            int idx = 0;
#pragma unroll
            for (int b = 0; b < 16; ++b) {
                float wraw = (b < 8) ? bf2f(uw0[b]) : bf2f(uw1[b - 8]);
                float hraw = (b < 8) ? bf2f(uh0[b]) : bf2f(uh1[b - 8]);
                cumw += MBWF + fw * __expf(wraw - mw);
                cumh += MBHF + fh * __expf(hraw - mh);
                float cwn = (b == 15) ? BOUNDF : (2.f * BOUNDF * cumw - BOUNDF);
                float chn = (b == 15) ? BOUNDF : (2.f * BOUNDF * cumh - BOUNDF);
                bool sel = (yc >= chh);
                iw  = sel ? (cwn - cw)  : iw;
                icw = sel ? cw          : icw;
                ih  = sel ? (chn - chh) : ih;
                ich = sel ? chh         : ich;
                idx = sel ? b           : idx;
                cw = cwn; chh = chn;
            }
            // selected-bin-only d (softplus x2) and lambda (sigmoid x1), runtime LDS reads
            float dm1 = bf2f(pr[(base + 32 + idx - 1) ^ xr]);   // unused value when idx==0
            float d0  = bf2f(pr[(base + 32 + idx) ^ xr]);       // pad slot when idx==15
            float idv   = (idx == 0)  ? (1.f - MDF) : (MDF + softplus_fast(dm1));
            float idvp1 = (idx == 15) ? (1.f - MDF) : (MDF + softplus_fast(d0));
            float lraw = bf2f(pr[(base + 48 + idx) ^ xr]);
            float il = MLF + (1.f - 2.f * MLF) / (1.f + __expf(-lraw));
            float x, lv;
            rls_core(y, iw, icw, ih, ich, il, idv, idvp1, &x, &lv);
            zs[row][16 + j] = x;
            atomicAdd(&lacc[row], lv);
        }
        __syncthreads();
    }
}

// ---------------- fused main kernel ----------------
__global__ __launch_bounds__(512, 4) void fused_kernel(
        const float* __restrict__ data, const float* __restrict__ means,
        const float* __restrict__ stds, const float* __restrict__ ws,
        const unsigned short* __restrict__ w2t, const unsigned short* __restrict__ w3t,
        const float* __restrict__ t2W1, const float* __restrict__ t2b1, const float* __restrict__ t2b2,
        const float* __restrict__ t1W1, const float* __restrict__ t1b1, const float* __restrict__ t1b2,
        float* __restrict__ out) {
    __shared__ float zs[32][33];
    __shared__ float lacc[32];
    __shared__ unsigned short h1b[32 * 320];
    __shared__ unsigned short h2b[32 * 320];
    __shared__ unsigned short pts[32 * 520];
    // LDS total: 4224+128+20480+20480+33280 = 78592 B -> 2 blocks/CU

    const int t = threadIdx.x;
    const int n0 = blockIdx.x * 32;

    {
        const float2* dp = (const float2*)(data + (size_t)n0 * DD);
        float2 v = dp[t];
        int row = t >> 4, c = (t & 15) * 2;
        zs[row][c]     = (v.x - means[c])     / (10.f * stds[c]);
        zs[row][c + 1] = (v.y - means[c + 1]) / (10.f * stds[c + 1]);
        if (t < 32) lacc[t] = 0.f;
    }
    __syncthreads();

    const float* tbl_t1 = ws + WS_TBL;
    const float* tbl_t2 = ws + WS_TBL + 16 * TBL_STRIDE;
    const float* b3p    = ws + WS_B3P;

    coupling(t, zs, lacc, h1b, h2b, pts, tbl_t2, t2W1, t2b1,
             w2t, t2b2, w3t, b3p);
    coupling(t, zs, lacc, h1b, h2b, pts, tbl_t1, t1W1, t1b1,
             w2t + 102400, t1b2, w3t + 327680, b3p + 1024);

    if (t < 32) {
        float lp = ws[WS_LP];
        float ss = 0.f;
#pragma unroll
        for (int c = 0; c < DD; ++c) ss += zs[t][c] * zs[t][c];
        out[n0 + t] = -0.5f * ss - 16.f * LOG2PIF + lacc[t] + lp;
    }
}

extern "C" void kernel_launch(void* const* d_in, const int* in_sizes, int n_in,
                              void* d_out, int out_size, void* d_ws, size_t ws_size,
                              hipStream_t stream) {
    const float* data  = (const float*)d_in[0];
    const float* means = (const float*)d_in[1];
    const float* stds  = (const float*)d_in[2];
    const float* t1w = (const float*)d_in[3];
    const float* t1h = (const float*)d_in[4];
    const float* t1d = (const float*)d_in[5];
    const float* t1l = (const float*)d_in[6];
    const float* t1W1 = (const float*)d_in[7];
    const float* t1b1 = (const float*)d_in[8];
    const float* t1W2 = (const float*)d_in[9];
    const float* t1b2 = (const float*)d_in[10];
    const float* t1W3 = (const float*)d_in[11];
    const float* t1b3 = (const float*)d_in[12];
    const float* t2w = (const float*)d_in[13];
    const float* t2h = (const float*)d_in[14];
    const float* t2d = (const float*)d_in[15];
    const float* t2l = (const float*)d_in[16];
    const float* t2W1 = (const float*)d_in[17];
    const float* t2b1 = (const float*)d_in[18];
    const float* t2W2 = (const float*)d_in[19];
    const float* t2b2 = (const float*)d_in[20];
    const float* t2W3 = (const float*)d_in[21];
    const float* t2b3 = (const float*)d_in[22];

    float* ws = (float*)d_ws;
    unsigned short* w2t = (unsigned short*)((char*)d_ws + W2T_BYTE);
    unsigned short* w3t = (unsigned short*)((char*)d_ws + W3T_BYTE);
    float* b3p = ws + WS_B3P;

    prep_tables<<<1, 64, 0, stream>>>(t1w, t1h, t1d, t1l, t2w, t2h, t2d, t2l, stds, ws);
    prep_weights<<<1684, 512, 0, stream>>>(t2W2, t1W2, t2W3, t1W3, t2b3, t1b3, w2t, w3t, b3p);
    fused_kernel<<<NROWS / 32, 512, 0, stream>>>(
        data, means, stds, ws, w2t, w3t,
        t2W1, t2b1, t2b2, t1W1, t1b1, t1b2, (float*)d_out);
}

// Round 6
// 567.871 us; speedup vs baseline: 9.5791x; 1.1090x over previous
//
#include <hip/hip_runtime.h>
#include <math.h>

#define NROWS 32768
#define DD 32
#define HID 320
#define NBINS 16
#define BOUNDF 3.0f
#define MBWF 0.001f
#define MBHF 0.001f
#define MDF 0.001f
#define MLF 0.025f
#define LOG2PIF 1.8378770664093453f

// ---------------- ws layout ----------------
#define WS_LP 0
#define WS_TBL 16
#define TBL_STRIDE 112
#define WS_B3P 4096          // 2 x 1024 floats (slot 0 = t2, slot 1 = t1)
#define W2T_BYTE 32768       // 2 x 320*320 ushort
#define W3T_BYTE 442368      // 2 x 1024*320 ushort

typedef __attribute__((ext_vector_type(8))) unsigned short ushort8_t;
typedef __attribute__((ext_vector_type(8))) __bf16 bf16x8;
typedef __attribute__((ext_vector_type(4))) float f32x4;

__device__ __forceinline__ unsigned short f2bf(float x) {   // RNE, pure-int (finite inputs)
    unsigned u = __builtin_bit_cast(unsigned, x);
    return (unsigned short)((u + 0x7FFFu + ((u >> 16) & 1u)) >> 16);
}
__device__ __forceinline__ float bf2f(unsigned short s) {
    return __builtin_bit_cast(float, (unsigned)s << 16);
}
__device__ __forceinline__ f32x4 mfma_bf16(ushort8_t a, ushort8_t b, f32x4 c) {
    return __builtin_amdgcn_mfma_f32_16x16x32_bf16(
        __builtin_bit_cast(bf16x8, a), __builtin_bit_cast(bf16x8, b), c, 0, 0, 0);
}

__device__ __forceinline__ float softplus_precise(float x) {
    return (x > 0.f) ? (x + log1pf(expf(-x))) : log1pf(expf(x));
}
__device__ __forceinline__ float softplus_fast(float x) {
    return fmaxf(x, 0.f) + __logf(1.f + __expf(-fabsf(x)));
}

// Inverse monotonic rational-linear spline, selected-bin core (fast-log variant).
__device__ __forceinline__ void rls_core(float y, float iw, float icw, float ih, float ich,
                                         float il, float idv, float idvp1,
                                         float* xo, float* lo_) {
    bool inside = (y >= -BOUNDF) && (y <= BOUNDF);
    float yc = fminf(fmaxf(y, -BOUNDF), BOUNDF);
    float idel = ih / iw;
    float wb = sqrtf(idv / idvp1);
    float wc = (il * idv + (1.f - il) * wb * idvp1) / idel;
    float ya = ich;
    float yb = ih + ich;
    float ym = ((1.f - il) * ya + il * wb * yb) / ((1.f - il) + il * wb);
    bool left = (yc <= ym);
    float num = left ? (il * (ya - yc)) : ((wc - il * wb) * yc + il * wb * yb - wc * ym);
    float den = left ? ((wc - 1.f) * yc + ya - wc * ym) : ((wc - wb) * yc + wb * yb - wc * ym);
    float x = num / den * iw + icw;
    float dnum = (left ? (wc * il * (ym - ya)) : (wb * wc * (1.f - il) * (yb - ym))) * iw;
    float ladj = __logf(dnum) - 2.f * __logf(fabsf(den));
    *xo = inside ? x : y;
    *lo_ = inside ? ladj : 0.f;
}

// permuted W3 column map: np in [0,1024) -> original p column (or -1 = zero pad)
__device__ __forceinline__ int colmap(int np) {
    int j = np >> 6, s = np & 63;
    if (s < 16) return j * 16 + s;
    if (s < 32) return 256 + j * 16 + (s - 16);
    if (s < 47) return 512 + j * 15 + (s - 32);
    if (s == 47) return -1;
    return 752 + j * 16 + (s - 48);
}

// ---- prep 1: spline1 tables + lp_aff (1 block, 64 threads). c=0 -> t1, c=1 -> t2.
__global__ void prep_tables(const float* __restrict__ t1w, const float* __restrict__ t1h,
                            const float* __restrict__ t1d, const float* __restrict__ t1l,
                            const float* __restrict__ t2w, const float* __restrict__ t2h,
                            const float* __restrict__ t2d, const float* __restrict__ t2l,
                            const float* __restrict__ stds, float* __restrict__ ws) {
    int td = threadIdx.x;
    if (td == 32) {
        float lp = 0.f;
        for (int k = 0; k < DD; ++k) lp -= logf(10.f * stds[k]);
        ws[WS_LP] = lp;
    }
    if (td < 32) {
        int c = td >> 4, j = td & 15;
        const float* wr = (c == 0 ? t1w : t2w) + j * NBINS;
        const float* hr = (c == 0 ? t1h : t2h) + j * NBINS;
        const float* dr = (c == 0 ? t1d : t2d) + j * (NBINS - 1);
        const float* lr = (c == 0 ? t1l : t2l) + j * NBINS;
        float* tb = ws + WS_TBL + (c * 16 + j) * TBL_STRIDE;
        float mw = -1e30f, mh = -1e30f;
        for (int b = 0; b < NBINS; ++b) { mw = fmaxf(mw, wr[b]); mh = fmaxf(mh, hr[b]); }
        float sw = 0.f, sh = 0.f;
        for (int b = 0; b < NBINS; ++b) { sw += expf(wr[b] - mw); sh += expf(hr[b] - mh); }
        float fw = (1.f - NBINS * MBWF) / sw;
        float fh = (1.f - NBINS * MBHF) / sh;
        float kx[17], ky[17];
        kx[0] = -BOUNDF; ky[0] = -BOUNDF;
        float cw = 0.f, ch = 0.f;
        for (int b = 0; b < NBINS; ++b) {
            cw += MBWF + fw * expf(wr[b] - mw);
            ch += MBHF + fh * expf(hr[b] - mh);
            kx[b + 1] = 2.f * BOUNDF * cw - BOUNDF;
            ky[b + 1] = 2.f * BOUNDF * ch - BOUNDF;
        }
        kx[16] = BOUNDF; ky[16] = BOUNDF;
        for (int b = 0; b < 17; ++b) { tb[b] = ky[b]; tb[17 + b] = kx[b]; }
        tb[34] = 1.f - MDF;
        for (int b = 1; b <= 15; ++b) tb[34 + b] = MDF + softplus_precise(dr[b - 1]);
        tb[50] = 1.f - MDF;
        for (int b = 0; b < NBINS; ++b) {
            tb[51 + b] = kx[b + 1] - kx[b];
            tb[67 + b] = ky[b + 1] - ky[b];
            tb[83 + b] = MLF + (1.f - 2.f * MLF) / (1.f + expf(-lr[b]));
        }
    }
}

// ---- prep 2: bf16 transposed weights into ws. slot 0 = t2, slot 1 = t1.
__global__ void prep_weights(const float* __restrict__ t2W2, const float* __restrict__ t1W2,
                             const float* __restrict__ t2W3, const float* __restrict__ t1W3,
                             const float* __restrict__ t2b3, const float* __restrict__ t1b3,
                             unsigned short* __restrict__ w2t, unsigned short* __restrict__ w3t,
                             float* __restrict__ b3p) {
    int id = blockIdx.x * 512 + threadIdx.x;
    if (id < 204800) {                       // W2t[c][n*320+k] = W2_c[k][n]
        int c = id / 102400;
        int rem = id - c * 102400;
        int k = rem / 320, n = rem - k * 320;
        const float* W2 = c ? t1W2 : t2W2;
        w2t[c * 102400 + n * 320 + k] = f2bf(W2[k * 320 + n]);
    } else if (id < 860160) {                // W3t[c][np*320+k] = W3_c[k][colmap(np)]
        int id2 = id - 204800;
        int c = id2 / 327680;
        int rem = id2 - c * 327680;
        int k = rem / 1024, np = rem - k * 1024;
        int col = colmap(np);
        const float* W3 = c ? t1W3 : t2W3;
        w3t[(size_t)c * 327680 + (size_t)np * 320 + k] =
            f2bf(col < 0 ? 0.f : W3[(size_t)k * 1008 + col]);
    } else if (id < 862208) {                // b3p
        int idb = id - 860160;
        int c = idb / 1024, np = idb - c * 1024;
        int col = colmap(np);
        const float* b3 = c ? t1b3 : t2b3;
        b3p[c * 1024 + np] = (col < 0) ? 0.f : b3[col];
    }
}

// ---------------- fused coupling (device fn, called twice) ----------------
__device__ __forceinline__ void coupling(
        int t, float (*zs)[33], float* lacc,
        unsigned short* h1b, unsigned short* h2b, unsigned short* pts,
        const float* __restrict__ tbl,
        const float* __restrict__ W1, const float* __restrict__ b1,
        const unsigned short* __restrict__ w2t, const float* __restrict__ b2,
        const unsigned short* __restrict__ w3t, const float* __restrict__ b3p) {
    const int l = t & 63, w = t >> 6;
    const int wm = w >> 2, wn = w & 3;

    // ---- phase 1: spline1 on dims 0..15 (1 task/thread) ----
    {
        int row = t >> 4, jd = t & 15;
        float y1 = zs[row][jd];
        const float* tb = tbl + jd * TBL_STRIDE;
        float yc = fminf(fmaxf(y1, -BOUNDF), BOUNDF);
        int idx = 0;
#pragma unroll
        for (int b = 1; b <= 16; ++b) idx += (yc >= tb[b]) ? 1 : 0;
        if (idx > 15) idx = 15;
        float x, lv;
        rls_core(y1, tb[51 + idx], tb[17 + idx], tb[67 + idx], tb[idx],
                 tb[83 + idx], tb[34 + idx], tb[35 + idx], &x, &lv);
        zs[row][jd] = x;
        atomicAdd(&lacc[row], lv);
    }
    __syncthreads();

    // ---- phase 2: h1 = relu(x1 @ W1 + b1), fp32 VALU (K=16) -> swizzled bf16 LDS ----
    {
        int cb = t & 63, rg = t >> 6;
        float acc[4][5];
#pragma unroll
        for (int j = 0; j < 5; ++j) {
            float bv = b1[cb + 64 * j];
#pragma unroll
            for (int i = 0; i < 4; ++i) acc[i][j] = bv;
        }
#pragma unroll
        for (int k = 0; k < 16; ++k) {
            float xv[4];
#pragma unroll
            for (int i = 0; i < 4; ++i) xv[i] = zs[rg * 4 + i][k];
#pragma unroll
            for (int j = 0; j < 5; ++j) {
                float wv = W1[k * HID + cb + 64 * j];
#pragma unroll
                for (int i = 0; i < 4; ++i) acc[i][j] += xv[i] * wv;
            }
        }
#pragma unroll
        for (int i = 0; i < 4; ++i) {
            int row = rg * 4 + i;
#pragma unroll
            for (int j = 0; j < 5; ++j) {
                int col = cb + 64 * j;
                h1b[row * 320 + (col ^ ((row & 7) << 3))] = f2bf(fmaxf(acc[i][j], 0.f));
            }
        }
    }
    __syncthreads();

    // ---- phase 3: h2 = relu(h1 @ W2 + b2) via MFMA (M=32,N=320,K=320) ----
    {
        const int mrow = wm * 16 + (l & 15);
        const int koff = (l >> 4) << 3;
        f32x4 acc[5];
        f32x4 z4 = {0.f, 0.f, 0.f, 0.f};
#pragma unroll
        for (int nt = 0; nt < 5; ++nt) acc[nt] = z4;
#pragma unroll
        for (int kt = 0; kt < 10; ++kt) {
            int k = kt * 32 + koff;
            ushort8_t a8 = *(const ushort8_t*)&h1b[mrow * 320 + (k ^ ((mrow & 7) << 3))];
#pragma unroll
            for (int nt = 0; nt < 5; ++nt) {
                int n = wn * 80 + nt * 16 + (l & 15);
                ushort8_t b8 = *(const ushort8_t*)&w2t[n * 320 + k];
                acc[nt] = mfma_bf16(a8, b8, acc[nt]);
            }
        }
#pragma unroll
        for (int nt = 0; nt < 5; ++nt) {
            int n = wn * 80 + nt * 16 + (l & 15);
            float bias = b2[n];
#pragma unroll
            for (int r = 0; r < 4; ++r) {
                int row = wm * 16 + ((l >> 4) << 2) + r;
                float v = fmaxf(acc[nt][r] + bias, 0.f);
                h2b[row * 320 + (n ^ ((row & 7) << 3))] = f2bf(v);
            }
        }
    }
    __syncthreads();

    // ---- phase 4+5: p-chunk GEMM (N=512) then in-register spline2 (8 dims/chunk) ----
    for (int ch = 0; ch < 2; ++ch) {
        {
            const int mrow = wm * 16 + (l & 15);
            const int koff = (l >> 4) << 3;
            f32x4 acc[8];
            f32x4 z4 = {0.f, 0.f, 0.f, 0.f};
#pragma unroll
            for (int nt = 0; nt < 8; ++nt) acc[nt] = z4;
#pragma unroll
            for (int kt = 0; kt < 10; ++kt) {
                int k = kt * 32 + koff;
                ushort8_t a8 = *(const ushort8_t*)&h2b[mrow * 320 + (k ^ ((mrow & 7) << 3))];
#pragma unroll
                for (int nt = 0; nt < 8; ++nt) {
                    int ng = ch * 512 + wn * 128 + nt * 16 + (l & 15);
                    ushort8_t b8 = *(const ushort8_t*)&w3t[(size_t)ng * 320 + k];
                    acc[nt] = mfma_bf16(a8, b8, acc[nt]);
                }
            }
#pragma unroll
            for (int nt = 0; nt < 8; ++nt) {
                int ng = ch * 512 + wn * 128 + nt * 16 + (l & 15);
                float bias = b3p[ng];
                int nl = wn * 128 + nt * 16 + (l & 15);   // chunk-local col
                int js = nl >> 6;
#pragma unroll
                for (int r = 0; r < 4; ++r) {
                    int row = wm * 16 + ((l >> 4) << 2) + r;
                    pts[row * 520 + (nl ^ (js << 3))] = f2bf(acc[nt][r] + bias);
                }
            }
        }
        __syncthreads();
        // ---- spline2: no big register arrays, no scratch, fast transcendentals ----
        if (t < 256) {
            int row = t >> 3, jl = t & 7;
            int j = ch * 8 + jl;
            float y = zs[row][16 + j];
            const unsigned short* pr = &pts[row * 520];
            const int base = jl * 64, xr = jl << 3;
            // w_raw (s 0..15), h_raw (s 16..31) into 4x ushort8 (16 VGPRs, static extract)
            ushort8_t uw0 = *(const ushort8_t*)&pr[(base + 0) ^ xr];
            ushort8_t uw1 = *(const ushort8_t*)&pr[(base + 8) ^ xr];
            ushort8_t uh0 = *(const ushort8_t*)&pr[(base + 16) ^ xr];
            ushort8_t uh1 = *(const ushort8_t*)&pr[(base + 24) ^ xr];
            float mw = -1e30f, mh = -1e30f;
#pragma unroll
            for (int b = 0; b < 8; ++b) {
                mw = fmaxf(mw, fmaxf(bf2f(uw0[b]), bf2f(uw1[b])));
                mh = fmaxf(mh, fmaxf(bf2f(uh0[b]), bf2f(uh1[b])));
            }
            float sw = 0.f, sh = 0.f;
#pragma unroll
            for (int b = 0; b < 8; ++b) {
                sw += __expf(bf2f(uw0[b]) - mw) + __expf(bf2f(uw1[b]) - mw);
                sh += __expf(bf2f(uh0[b]) - mh) + __expf(bf2f(uh1[b]) - mh);
            }
            float fw = (1.f - NBINS * MBWF) / sw;
            float fh = (1.f - NBINS * MBHF) / sh;
            float yc = fminf(fmaxf(y, -BOUNDF), BOUNDF);
            float cw = -BOUNDF, chh = -BOUNDF, cumw = 0.f, cumh = 0.f;
            float iw = 1.f, icw = 0.f, ih = 1.f, ich = 0.f;
            int idx = 0;
#pragma unroll
            for (int b = 0; b < 16; ++b) {
                float wraw = (b < 8) ? bf2f(uw0[b]) : bf2f(uw1[b - 8]);
                float hraw = (b < 8) ? bf2f(uh0[b]) : bf2f(uh1[b - 8]);
                cumw += MBWF + fw * __expf(wraw - mw);
                cumh += MBHF + fh * __expf(hraw - mh);
                float cwn = (b == 15) ? BOUNDF : (2.f * BOUNDF * cumw - BOUNDF);
                float chn = (b == 15) ? BOUNDF : (2.f * BOUNDF * cumh - BOUNDF);
                bool sel = (yc >= chh);
                iw  = sel ? (cwn - cw)  : iw;
                icw = sel ? cw          : icw;
                ih  = sel ? (chn - chh) : ih;
                ich = sel ? chh         : ich;
                idx = sel ? b           : idx;
                cw = cwn; chh = chn;
            }
            // selected-bin-only d (softplus x2) and lambda (sigmoid x1), runtime LDS reads
            float dm1 = bf2f(pr[(base + 32 + idx - 1) ^ xr]);   // unused value when idx==0
            float d0  = bf2f(pr[(base + 32 + idx) ^ xr]);       // pad slot when idx==15
            float idv   = (idx == 0)  ? (1.f - MDF) : (MDF + softplus_fast(dm1));
            float idvp1 = (idx == 15) ? (1.f - MDF) : (MDF + softplus_fast(d0));
            float lraw = bf2f(pr[(base + 48 + idx) ^ xr]);
            float il = MLF + (1.f - 2.f * MLF) / (1.f + __expf(-lraw));
            float x, lv;
            rls_core(y, iw, icw, ih, ich, il, idv, idvp1, &x, &lv);
            zs[row][16 + j] = x;
            atomicAdd(&lacc[row], lv);
        }
        __syncthreads();
    }
}

// ---------------- fused main kernel ----------------
// launch_bounds (512, 2): 256-VGPR/thread budget -> no scratch spill (round-3/4 lesson:
// (512,4)'s 128-reg cap spilled ~200 B/thread = 100+ MB of HBM round-trips).
__global__ __launch_bounds__(512, 2) void fused_kernel(
        const float* __restrict__ data, const float* __restrict__ means,
        const float* __restrict__ stds, const float* __restrict__ ws,
        const unsigned short* __restrict__ w2t, const unsigned short* __restrict__ w3t,
        const float* __restrict__ t2W1, const float* __restrict__ t2b1, const float* __restrict__ t2b2,
        const float* __restrict__ t1W1, const float* __restrict__ t1b1, const float* __restrict__ t1b2,
        float* __restrict__ out) {
    __shared__ float zs[32][33];
    __shared__ float lacc[32];
    __shared__ unsigned short h1b[32 * 320];
    __shared__ unsigned short h2b[32 * 320];
    __shared__ unsigned short pts[32 * 520];
    // LDS total: 4224+128+20480+20480+33280 = 78592 B

    const int t = threadIdx.x;
    const int n0 = blockIdx.x * 32;

    {
        const float2* dp = (const float2*)(data + (size_t)n0 * DD);
        float2 v = dp[t];
        int row = t >> 4, c = (t & 15) * 2;
        zs[row][c]     = (v.x - means[c])     / (10.f * stds[c]);
        zs[row][c + 1] = (v.y - means[c + 1]) / (10.f * stds[c + 1]);
        if (t < 32) lacc[t] = 0.f;
    }
    __syncthreads();

    const float* tbl_t1 = ws + WS_TBL;
    const float* tbl_t2 = ws + WS_TBL + 16 * TBL_STRIDE;
    const float* b3p    = ws + WS_B3P;

    coupling(t, zs, lacc, h1b, h2b, pts, tbl_t2, t2W1, t2b1,
             w2t, t2b2, w3t, b3p);
    coupling(t, zs, lacc, h1b, h2b, pts, tbl_t1, t1W1, t1b1,
             w2t + 102400, t1b2, w3t + 327680, b3p + 1024);

    if (t < 32) {
        float lp = ws[WS_LP];
        float ss = 0.f;
#pragma unroll
        for (int c = 0; c < DD; ++c) ss += zs[t][c] * zs[t][c];
        out[n0 + t] = -0.5f * ss - 16.f * LOG2PIF + lacc[t] + lp;
    }
}

extern "C" void kernel_launch(void* const* d_in, const int* in_sizes, int n_in,
                              void* d_out, int out_size, void* d_ws, size_t ws_size,
                              hipStream_t stream) {
    const float* data  = (const float*)d_in[0];
    const float* means = (const float*)d_in[1];
    const float* stds  = (const float*)d_in[2];
    const float* t1w = (const float*)d_in[3];
    const float* t1h = (const float*)d_in[4];
    const float* t1d = (const float*)d_in[5];
    const float* t1l = (const float*)d_in[6];
    const float* t1W1 = (const float*)d_in[7];
    const float* t1b1 = (const float*)d_in[8];
    const float* t1W2 = (const float*)d_in[9];
    const float* t1b2 = (const float*)d_in[10];
    const float* t1W3 = (const float*)d_in[11];
    const float* t1b3 = (const float*)d_in[12];
    const float* t2w = (const float*)d_in[13];
    const float* t2h = (const float*)d_in[14];
    const float* t2d = (const float*)d_in[15];
    const float* t2l = (const float*)d_in[16];
    const float* t2W1 = (const float*)d_in[17];
    const float* t2b1 = (const float*)d_in[18];
    const float* t2W2 = (const float*)d_in[19];
    const float* t2b2 = (const float*)d_in[20];
    const float* t2W3 = (const float*)d_in[21];
    const float* t2b3 = (const float*)d_in[22];

    float* ws = (float*)d_ws;
    unsigned short* w2t = (unsigned short*)((char*)d_ws + W2T_BYTE);
    unsigned short* w3t = (unsigned short*)((char*)d_ws + W3T_BYTE);
    float* b3p = ws + WS_B3P;

    prep_tables<<<1, 64, 0, stream>>>(t1w, t1h, t1d, t1l, t2w, t2h, t2d, t2l, stds, ws);
    prep_weights<<<1684, 512, 0, stream>>>(t2W2, t1W2, t2W3, t1W3, t2b3, t1b3, w2t, w3t, b3p);
    fused_kernel<<<NROWS / 32, 512, 0, stream>>>(
        data, means, stds, ws, w2t, w3t,
        t2W1, t2b1, t2b2, t1W1, t1b1, t1b2, (float*)d_out);
}